// Round 16
// baseline (183.603 us; speedup 1.0000x reference)
//
#include <hip/hip_runtime.h>
#include <math.h>

#define NB 16
#define CC 512
#define CQ 64
#define HWN 1024

typedef float4 f4;
typedef __bf16 bf16x8 __attribute__((ext_vector_type(8)));
typedef float f32x4 __attribute__((ext_vector_type(4)));
typedef __attribute__((ext_vector_type(8))) unsigned short ushort8v;

__device__ __forceinline__ unsigned short f2bf(float f) {
    unsigned int u = __float_as_uint(f);
    u = (u + 0x7fffu + ((u >> 16) & 1u)) >> 16;
    return (unsigned short)u;
}
__device__ __forceinline__ float bf2f(unsigned short u) {
    return __uint_as_float(((unsigned int)u) << 16);
}

__device__ __forceinline__ void gload16(const unsigned short* g, unsigned short* l) {
    __builtin_amdgcn_global_load_lds(
        (const __attribute__((address_space(1))) unsigned int*)g,
        (__attribute__((address_space(3))) unsigned int*)l,
        16, 0, 0);
}

// ---------------------------------------------------------------------------
// Generalized NT bf16 MFMA GEMM, 2-phase double-buffered (validated r5-r13).
// BK in {64,32}; BN in {128,64}. Swizzle involutions (r13-verified):
//   BK=64: f(r) = r & 7        (0 conflicts, r8-r13)
//   BK=32: f(r) = (r>>1) & 3   (covers (parity,slot) bank-groups 2-way)
// STATS: per-(wave,row) partials to unique slots, stride 512 (supports
// gx up to 16 N-tiles x 16 batches x 2 wave-halves).
// ---------------------------------------------------------------------------
template<int BM, int BN, int BK, int BIAS, bool OBF16, int ZSH, bool STATS>
__global__ __launch_bounds__(256)
void mfma_g(const unsigned short* __restrict__ A, long sAlo, long sAhi, int lda,
            const unsigned short* __restrict__ B, long sBlo, long sBhi, int ldb,
            const float* __restrict__ bias, long sBiasHi,
            void* __restrict__ Cout, long sClo, long sChi, int ldc,
            int Ksize, float alpha, float* __restrict__ statsAcc)
{
    constexpr int MF  = BM / 32;           // 16-row frags per wave (M)
    constexpr int NF  = BN / 32;
    constexpr int LPR = BK / 8;            // lanes per LDS row (8 or 4)
    constexpr int RPG = 64 / LPR;          // rows per gload (8 or 16)
    constexpr int CA  = BM / RPG / 4;      // gloads per wave for A
    constexpr int CB  = BN / RPG / 4;
    constexpr int SWM = LPR - 1;           // swizzle mask (7 or 3)
    constexpr int SSH = (BK == 64) ? 0 : 1; // swizzle row shift
    __shared__ unsigned short As[2][BM * BK];
    __shared__ unsigned short Bs[2][BN * BK];

    // XCD-chunked bijective swizzle: physical p -> logical (p%8)*(n/8)+p/8
    const int gx = gridDim.x, gy = gridDim.y;
    int f = blockIdx.x + gx * (blockIdx.y + gy * blockIdx.z);
    const int nwg = gx * gy * gridDim.z;
    f = (f & 7) * (nwg >> 3) + (f >> 3);
    const int bx = f % gx; const int t2 = f / gx;
    const int by = t2 % gy; const int bz = t2 / gy;

    const int zlo = ZSH ? (bz & ((1 << ZSH) - 1)) : 0;
    const int zhi = bz >> ZSH;

    const int t = threadIdx.x, lane = t & 63, wid = t >> 6;
    const int wm = (wid >> 1) * (BM / 2), wn = (wid & 1) * (BN / 2);
    const int m0 = by * BM, n0 = bx * BN;
    const unsigned short* Ab = A + (long)zlo * sAlo + (long)zhi * sAhi;
    const unsigned short* Bb = B + (long)zlo * sBlo + (long)zhi * sBhi;

    // staging: each gload = RPG rows x BK*2 bytes; source col pre-swizzled
    const int srow = lane / LPR;                 // row within gload
    const int slt  = lane & SWM;                 // 16B slot
    const int scol = ((slt ^ ((srow >> SSH) & SWM)) << 3);
    const unsigned short* gA[CA]; const unsigned short* gB[CB];
    unsigned short* lA[CA]; unsigned short* lB[CB];
#pragma unroll
    for (int c = 0; c < CA; ++c) {
        const int seg = wid + 4 * c;
        gA[c] = Ab + (long)(m0 + seg * RPG + srow) * lda + scol;
        lA[c] = &As[0][seg * 512];               // RPG*BK = 512 ushorts always
    }
#pragma unroll
    for (int c = 0; c < CB; ++c) {
        const int seg = wid + 4 * c;
        gB[c] = Bb + (long)(n0 + seg * RPG + srow) * ldb + scol;
        lB[c] = &Bs[0][seg * 512];
    }

    f32x4 acc[MF][NF] = {};
    const int l15 = lane & 15, q = lane >> 4;    // k-octet 0..3

    // prologue: stage tile 0 into buf 0, drain
#pragma unroll
    for (int c = 0; c < CA; ++c) gload16(gA[c], lA[c]);
#pragma unroll
    for (int c = 0; c < CB; ++c) gload16(gB[c], lB[c]);
    __syncthreads();

    const int nt = Ksize / BK;
    int cur = 0;
    for (int tt = 0; tt < nt; ++tt) {
        if (tt + 1 < nt) {                       // issue next-tile loads FIRST
            const int ko = (tt + 1) * BK;
            const int nb = cur ^ 1;
#pragma unroll
            for (int c = 0; c < CA; ++c) gload16(gA[c] + ko, lA[c] + nb * (BM * BK));
#pragma unroll
            for (int c = 0; c < CB; ++c) gload16(gB[c] + ko, lB[c] + nb * (BN * BK));
        }
        if (BK == 64) {
            bf16x8 alo[MF], ahi[MF], blo[NF], bhi[NF];
#pragma unroll
            for (int i = 0; i < MF; ++i) {
                const int r = wm + i * 16 + l15;
                alo[i] = *(const bf16x8*)&As[cur][r * 64 + ((q ^ (r & 7)) << 3)];
                ahi[i] = *(const bf16x8*)&As[cur][r * 64 + (((q + 4) ^ (r & 7)) << 3)];
            }
#pragma unroll
            for (int j = 0; j < NF; ++j) {
                const int r = wn + j * 16 + l15;
                blo[j] = *(const bf16x8*)&Bs[cur][r * 64 + ((q ^ (r & 7)) << 3)];
                bhi[j] = *(const bf16x8*)&Bs[cur][r * 64 + (((q + 4) ^ (r & 7)) << 3)];
            }
#pragma unroll
            for (int i = 0; i < MF; ++i)
#pragma unroll
                for (int j = 0; j < NF; ++j) {
                    acc[i][j] = __builtin_amdgcn_mfma_f32_16x16x32_bf16(alo[i], blo[j], acc[i][j], 0, 0, 0);
                    acc[i][j] = __builtin_amdgcn_mfma_f32_16x16x32_bf16(ahi[i], bhi[j], acc[i][j], 0, 0, 0);
                }
        } else {                                 // BK == 32, f(r) = (r>>1)&3
            bf16x8 av[MF], bv[NF];
#pragma unroll
            for (int i = 0; i < MF; ++i) {
                const int r = wm + i * 16 + l15;
                av[i] = *(const bf16x8*)&As[cur][r * 32 + ((q ^ ((r >> 1) & 3)) << 3)];
            }
#pragma unroll
            for (int j = 0; j < NF; ++j) {
                const int r = wn + j * 16 + l15;
                bv[j] = *(const bf16x8*)&Bs[cur][r * 32 + ((q ^ ((r >> 1) & 3)) << 3)];
            }
#pragma unroll
            for (int i = 0; i < MF; ++i)
#pragma unroll
                for (int j = 0; j < NF; ++j)
                    acc[i][j] = __builtin_amdgcn_mfma_f32_16x16x32_bf16(av[i], bv[j], acc[i][j], 0, 0, 0);
        }
        __syncthreads();                         // drains vmcnt: next buf ready
        cur ^= 1;
    }

    unsigned short* C16 = (unsigned short*)Cout + (long)zlo * sClo + (long)zhi * sChi;
    float*          C32 = (float*)Cout + (long)zlo * sClo + (long)zhi * sChi;
    const float* biasb = (BIAS != 0) ? bias + (long)zhi * sBiasHi : nullptr;
    const int r0 = q << 2;
#pragma unroll
    for (int i = 0; i < MF; ++i) {
#pragma unroll
        for (int r = 0; r < 4; ++r) {
            const int m = m0 + wm + i * 16 + r0 + r;
            const float brow = (BIAS == 1) ? biasb[m] : 0.0f;
            float ps = 0.0f, ps2 = 0.0f;
#pragma unroll
            for (int j = 0; j < NF; ++j) {
                const int n = n0 + wn + j * 16 + l15;
                const float bb = (BIAS == 2) ? biasb[n] : brow;
                const float o = alpha * (acc[i][j][r] + bb);
                if (OBF16) C16[(long)m * ldc + n] = f2bf(o);
                else       C32[(long)m * ldc + n] = o;
                if (STATS) { ps += o; ps2 += o * o; }   // pre-rounding fp32 stats
            }
            if (STATS) {
#pragma unroll
                for (int off = 8; off; off >>= 1) {
                    ps  += __shfl_xor(ps, off);
                    ps2 += __shfl_xor(ps2, off);
                }
                if (l15 == 0) {
                    const int slot2 = ((zlo * gx + bx) << 1) + (wid & 1);  // < 512
                    statsAcc[(long)m * 512 + slot2]          = ps;
                    statsAcc[262144 + (long)m * 512 + slot2] = ps2;
                }
            }
        }
    }
}

// ---------------------------------------------------------------------------
// Fused QK^T + softmax -> Pcat bf16, fully in-register (validated r10-r13).
// ---------------------------------------------------------------------------
__global__ __launch_bounds__(256)
void attn_fused3(const unsigned short* __restrict__ QK, unsigned short* __restrict__ Pcat)
{
    __shared__ float ws16[16][4];   // [row][wave] partial sums
    const int t = threadIdx.x, lane = t & 63, w = t >> 6;
    const int bx = blockIdx.x, b = blockIdx.y, dir = blockIdx.z;
    const unsigned short* Q = QK + (long)(dir ? b : 16 + b) * 131072;
    const unsigned short* K = QK + (long)(dir ? 16 + b : b) * 131072 + 64;
    const int l15 = lane & 15, slot = lane >> 4, kg = slot << 3;

    const long mrow = (long)bx * 16 + l15;
    bf16x8 aq0 = *(const bf16x8*)&Q[mrow * 128 + kg];
    bf16x8 aq1 = *(const bf16x8*)&Q[mrow * 128 + 32 + kg];

    const int colbase = w << 8;       // wave covers 256 kv cols
    const int rbase = slot << 2;
    f32x4 e[4][4];                    // e[c][j][r], static indexing only
    float rowp[4] = {0.0f, 0.0f, 0.0f, 0.0f};
#pragma unroll
    for (int c = 0; c < 4; ++c) {
        const int n0 = colbase + (c << 6);
        bf16x8 bk0[4], bk1[4];
#pragma unroll
        for (int j = 0; j < 4; ++j) {
            const long krow = n0 + (j << 4) + l15;
            bk0[j] = *(const bf16x8*)&K[krow * 128 + kg];
            bk1[j] = *(const bf16x8*)&K[krow * 128 + 32 + kg];
        }
#pragma unroll
        for (int j = 0; j < 4; ++j) {
            f32x4 a = {0.f, 0.f, 0.f, 0.f};
            a = __builtin_amdgcn_mfma_f32_16x16x32_bf16(aq0, bk0[j], a, 0, 0, 0);
            a = __builtin_amdgcn_mfma_f32_16x16x32_bf16(aq1, bk1[j], a, 0, 0, 0);
#pragma unroll
            for (int r = 0; r < 4; ++r) {
                const float ev = __expf(a[r]);
                e[c][j][r] = ev;
                rowp[r] += ev;
            }
        }
    }
#pragma unroll
    for (int off = 1; off < 16; off <<= 1) {
#pragma unroll
        for (int r = 0; r < 4; ++r) rowp[r] += __shfl_xor(rowp[r], off);
    }
    if (l15 == 0) {
#pragma unroll
        for (int r = 0; r < 4; ++r) ws16[rbase + r][w] = rowp[r];
    }
    __syncthreads();
    float inv[4];
#pragma unroll
    for (int r = 0; r < 4; ++r) {
        f4 s = *(const f4*)ws16[rbase + r];
        inv[r] = 1.0f / (s.x + s.y + s.z + s.w);
    }
    unsigned short* dstb = Pcat + ((long)(b * 1024 + bx * 16)) * 2048 + dir * 1024;
#pragma unroll
    for (int c = 0; c < 4; ++c) {
#pragma unroll
        for (int j = 0; j < 4; ++j) {
            const int col = colbase + (c << 6) + (j << 4) + l15;
#pragma unroll
            for (int r = 0; r < 4; ++r)
                dstb[(long)(rbase + r) * 2048 + col] = f2bf(e[c][j][r] * inv[r]);
        }
    }
}

// ---------------------------------------------------------------------------
// ALL prep in ONE dispatch (5377 blocks) — validated r12/r13.
// ---------------------------------------------------------------------------
__global__ __launch_bounds__(256)
void prep_all(const float* __restrict__ src_dep, const float* __restrict__ src_rgb,
              const float* __restrict__ Wv_dep, const float* __restrict__ Wv_rgb,
              const float* __restrict__ W_fuse,
              const float* __restrict__ wqd, const float* __restrict__ wkd,
              const float* __restrict__ wqr, const float* __restrict__ wkr,
              const float* __restrict__ bqd, const float* __restrict__ bkd,
              const float* __restrict__ bqr, const float* __restrict__ bkr,
              const float* __restrict__ bvd, const float* __restrict__ bvr,
              unsigned short* __restrict__ xT, unsigned short* __restrict__ WvT,
              unsigned short* __restrict__ Wfb, unsigned short* __restrict__ Wqk,
              float* __restrict__ bfuse, float* __restrict__ biascat, float s)
{
    __shared__ float tile[64][65];
    const int blk = blockIdx.x, t = threadIdx.x;

    if (blk < 4096) {                      // input transpose pair
        const int z = blk >> 7, rem = blk & 127;
        const int c0 = (rem & 15) << 6, r0 = (rem >> 4) << 6;
        const float* sp = (z < 16 ? src_dep : src_rgb) + (long)(z & 15) * 524288;
        unsigned short* d = xT + (long)z * 524288;
        const int lr = t >> 4, lc = (t & 15) << 2;
#pragma unroll
        for (int i = 0; i < 4; ++i) {
            f4 v = *(const f4*)(sp + (long)(r0 + lr + i * 16) * HWN + c0 + lc);
            *(f4*)&tile[lr + i * 16][lc] = v;
        }
        __syncthreads();
#pragma unroll
        for (int i = 0; i < 4; ++i) {
            const int crow = lr + i * 16;
            ushort4 o;
            o.x = f2bf(tile[lc + 0][crow]);
            o.y = f2bf(tile[lc + 1][crow]);
            o.z = f2bf(tile[lc + 2][crow]);
            o.w = f2bf(tile[lc + 3][crow]);
            *(ushort4*)&d[(long)(c0 + crow) * CC + r0 + lc] = o;
        }
    } else if (blk < 4224) {               // Wv transpose pair
        const int bb = blk - 4096;
        const int z = bb >> 6, tx = bb & 63;
        const float* src = z ? Wv_rgb : Wv_dep;
        unsigned short* d = WvT + (long)z * 262144;
        const int c0 = (tx & 7) << 6, r0 = (tx >> 3) << 6;
        const int lr = t >> 4, lc = (t & 15) << 2;
#pragma unroll
        for (int i = 0; i < 4; ++i) {
            f4 v = *(const f4*)(src + (long)(r0 + lr + i * 16) * CC + c0 + lc);
            *(f4*)&tile[lr + i * 16][lc] = v;
        }
        __syncthreads();
#pragma unroll
        for (int i = 0; i < 4; ++i) {
            const int crow = lr + i * 16;
            ushort4 o;
            o.x = f2bf(tile[lc + 0][crow]);
            o.y = f2bf(tile[lc + 1][crow]);
            o.z = f2bf(tile[lc + 2][crow]);
            o.w = f2bf(tile[lc + 3][crow]);
            *(ushort4*)&d[(long)(c0 + crow) * CC + r0 + lc] = o;
        }
    } else if (blk < 4736) {               // W_fuse flat cvt
        const int i4 = (blk - 4224) * 256 + t;
        f4 v = ((const f4*)W_fuse)[i4];
        ushort4 o;
        o.x = f2bf(v.x); o.y = f2bf(v.y); o.z = f2bf(v.z); o.w = f2bf(v.w);
        ((ushort4*)Wfb)[i4] = o;
    } else if (blk < 4864) {               // Wqk build
        const int i4 = (blk - 4736) * 256 + t;
        const int row = i4 >> 7;
        const int seg = row >> 6;
        const float* src = (seg == 0) ? wqd : (seg == 1) ? wkd : (seg == 2) ? wqr : wkr;
        const float sc = (seg & 1) ? 1.0f : s;
        f4 v = ((const f4*)src)[((row & 63) << 7) + (i4 & 127)];
        ushort4 o;
        o.x = f2bf(v.x * sc); o.y = f2bf(v.y * sc);
        o.z = f2bf(v.z * sc); o.w = f2bf(v.w * sc);
        ((ushort4*)Wqk)[i4] = o;
    } else if (blk < 5376) {               // bfuse
        const int o = blk - 4864;
        const float* row = W_fuse + (long)o * 1024;
        float sum = row[t] * bvd[t] + row[512 + t] * bvr[t]
                  + row[256 + t] * bvd[256 + t] + row[768 + t] * bvr[256 + t];
#pragma unroll
        for (int off = 32; off; off >>= 1) sum += __shfl_xor(sum, off);
        float* red = &tile[0][0];
        if ((t & 63) == 0) red[t >> 6] = sum;
        __syncthreads();
        if (t == 0) bfuse[o] = red[0] + red[1] + red[2] + red[3];
    } else {                               // biascat
        float v;
        if (t < 64)       v = bqd[t] * s;
        else if (t < 128) v = bkd[t - 64];
        else if (t < 192) v = bqr[t - 128] * s;
        else              v = bkr[t - 192];
        biascat[t] = v;
    }
}

// ---------------------------------------------------------------------------
// BN finalize + apply + ReLU in ONE kernel (r11-r13), now 512 stat slots:
// each thread sums slots t and t+256 before the shuffle reduce.
// ---------------------------------------------------------------------------
__global__ __launch_bounds__(256)
void bn_apply_f(const unsigned short* __restrict__ fused, const float* __restrict__ part,
                const float* __restrict__ gamma, const float* __restrict__ beta,
                float* __restrict__ out)
{
    __shared__ float red[4][4];   // [stat: s1c0,s2c0,s1c1,s2c1][wave]
    const int t = threadIdx.x, blk = blockIdx.x;
    const int c0 = (blk * 2) & 511, c1 = c0 + 1;
    float a = part[(long)c0 * 512 + t]          + part[(long)c0 * 512 + 256 + t];
    float b = part[262144 + (long)c0 * 512 + t] + part[262144 + (long)c0 * 512 + 256 + t];
    float c = part[(long)c1 * 512 + t]          + part[(long)c1 * 512 + 256 + t];
    float d = part[262144 + (long)c1 * 512 + t] + part[262144 + (long)c1 * 512 + 256 + t];
#pragma unroll
    for (int off = 32; off; off >>= 1) {
        a += __shfl_xor(a, off); b += __shfl_xor(b, off);
        c += __shfl_xor(c, off); d += __shfl_xor(d, off);
    }
    if ((t & 63) == 0) {
        const int w = t >> 6;
        red[0][w] = a; red[1][w] = b; red[2][w] = c; red[3][w] = d;
    }
    __syncthreads();
    const float S1a = red[0][0] + red[0][1] + red[0][2] + red[0][3];
    const float S2a = red[1][0] + red[1][1] + red[1][2] + red[1][3];
    const float S1b = red[2][0] + red[2][1] + red[2][2] + red[2][3];
    const float S2b = red[3][0] + red[3][1] + red[3][2] + red[3][3];
    const float mean0 = S1a * (1.0f / 16384.0f);
    const float is0   = rsqrtf(S2a * (1.0f / 16384.0f) - mean0 * mean0 + 1e-5f);
    const float mean1 = S1b * (1.0f / 16384.0f);
    const float is1   = rsqrtf(S2b * (1.0f / 16384.0f) - mean1 * mean1 + 1e-5f);

    const long i8 = (long)blk * 256 + t;         // ushort8 index
    const int  oc = (t >> 7) ? c1 : c0;
    const float mean = (t >> 7) ? mean1 : mean0;
    const float is   = (t >> 7) ? is1 : is0;
    ushort8v v = ((const ushort8v*)fused)[i8];
    const float g  = gamma[oc] * is;
    const float bb = beta[oc] - mean * g;
    f4 o0, o1;
    o0.x = fmaxf(fmaf(bf2f(v[0]), g, bb), 0.0f);
    o0.y = fmaxf(fmaf(bf2f(v[1]), g, bb), 0.0f);
    o0.z = fmaxf(fmaf(bf2f(v[2]), g, bb), 0.0f);
    o0.w = fmaxf(fmaf(bf2f(v[3]), g, bb), 0.0f);
    o1.x = fmaxf(fmaf(bf2f(v[4]), g, bb), 0.0f);
    o1.y = fmaxf(fmaf(bf2f(v[5]), g, bb), 0.0f);
    o1.z = fmaxf(fmaf(bf2f(v[6]), g, bb), 0.0f);
    o1.w = fmaxf(fmaf(bf2f(v[7]), g, bb), 0.0f);
    ((f4*)out)[i8 * 2]     = o0;
    ((f4*)out)[i8 * 2 + 1] = o1;
}

// ---------------------------------------------------------------------------
// Workspace layout (BYTE offsets). Total ~182 MB (< 218 MB proven available).
// ---------------------------------------------------------------------------
static constexpr long B_depT  = 0;          // bf16 (16,1024,512)
static constexpr long B_rgbT  = 16777216;
static constexpr long B_WvT1  = 33554432;   // bf16 512x512 (+WvT2 adjacent)
static constexpr long B_Wfb   = 34603008;   // bf16 512x1024
static constexpr long B_Wqk   = 35651584;   // bf16 256x512
static constexpr long B_Wc1   = 35913728;   // bf16 512x512 (+Wc2 adjacent)
static constexpr long B_bfu   = 36962304;   // fp32 512
static constexpr long B_bias  = 36964352;   // fp32 256
static constexpr long B_QK    = 36966400;   // bf16 (32,1024,128)
static constexpr long B_Acat  = 45355008;   // bf16 (16,512,2048)
static constexpr long B_Pcat  = 78909440;   // bf16 (16,1024,2048)
static constexpr long B_fused = 146018304;  // bf16 (16,512,1024)
static constexpr long B_part  = 179576832;  // fp32 524288 (sum[512x512] | sumsq)

extern "C" void kernel_launch(void* const* d_in, const int* in_sizes, int n_in,
                              void* d_out, int out_size, void* d_ws, size_t ws_size,
                              hipStream_t stream)
{
    const float* rgb    = (const float*)d_in[0];
    const float* depth  = (const float*)d_in[1];
    const float* Wq_rgb = (const float*)d_in[2];
    const float* bq_rgb = (const float*)d_in[3];
    const float* Wk_dep = (const float*)d_in[4];
    const float* bk_dep = (const float*)d_in[5];
    const float* Wv_dep = (const float*)d_in[6];
    const float* bv_dep = (const float*)d_in[7];
    const float* Wq_dep = (const float*)d_in[8];
    const float* bq_dep = (const float*)d_in[9];
    const float* Wk_rgb = (const float*)d_in[10];
    const float* bk_rgb = (const float*)d_in[11];
    const float* Wv_rgb = (const float*)d_in[12];
    const float* bv_rgb = (const float*)d_in[13];
    const float* W_fuse = (const float*)d_in[14];
    const float* gamma  = (const float*)d_in[15];
    const float* beta   = (const float*)d_in[16];
    char* ws = (char*)d_ws;
    float* out = (float*)d_out;

    const float inv_scale = 0.044194173824159223f;  // 1/sqrt(512)
    dim3 blk(256);

    unsigned short* depT = (unsigned short*)(ws + B_depT);
    unsigned short* WvT1 = (unsigned short*)(ws + B_WvT1);
    unsigned short* Wfb  = (unsigned short*)(ws + B_Wfb);
    unsigned short* Wqk  = (unsigned short*)(ws + B_Wqk);
    unsigned short* Wc1  = (unsigned short*)(ws + B_Wc1);
    float*          bfu  = (float*)(ws + B_bfu);
    float*          bias = (float*)(ws + B_bias);
    unsigned short* QK   = (unsigned short*)(ws + B_QK);
    unsigned short* Acat = (unsigned short*)(ws + B_Acat);
    unsigned short* Pcat = (unsigned short*)(ws + B_Pcat);
    unsigned short* fused= (unsigned short*)(ws + B_fused);
    float*          part = (float*)(ws + B_part);

    // --- single prep dispatch: input transpose + all weight prep ---
    prep_all<<<5377, blk, 0, stream>>>(depth, rgb, Wv_dep, Wv_rgb, W_fuse,
        Wq_dep, Wk_dep, Wq_rgb, Wk_rgb, bq_dep, bk_dep, bq_rgb, bk_rgb,
        bv_dep, bv_rgb, depT, WvT1, Wfb, Wqk, bfu, bias, inv_scale);

    // --- Wc pair (z=0: Wf[:,:512]@Wv_dep; z=1: Wf[:,512:]@Wv_rgb), BK=32 ---
    mfma_g<128, 128, 32, 0, true, 0, false><<<dim3(4, 4, 2), blk, 0, stream>>>(
        Wfb, 0, 512, 1024, WvT1, 0, 262144, 512, nullptr, 0,
        Wc1, 0, 262144, 512, 512, 1.0f, nullptr);

    // --- projections: BM=64, BK=32 -> grid 512 ---
    mfma_g<64, 128, 32, 2, true, 4, false><<<dim3(1, 16, 32), blk, 0, stream>>>(
        depT, 524288, 8388608, 512, Wqk, 0, 65536, 512, bias, 128,
        QK, 131072, 2097152, 128, 512, 1.0f, nullptr);

    // --- Acat: BK=32, 32KB LDS, 4 blocks/CU on 1024 blocks ---
    mfma_g<128, 128, 32, 0, true, 4, false><<<dim3(8, 4, 32), blk, 0, stream>>>(
        Wc1, 0, 262144, 512, depT, 524288, 8388608, 512, nullptr, 0,
        Acat, 1048576, 1024, 2048, 512, 1.0f, nullptr);

    // --- fused attention: QK^T + exp + in-register softmax -> Pcat ---
    attn_fused3<<<dim3(64, NB, 2), blk, 0, stream>>>(QK, Pcat);

    // --- fused(bf16) = Acat @ Pcat^T + bfuse (K=2048), BN=64 BK=32:
    //     grid (16,4,16) = 1024 blocks -> 4 blocks/CU (was 2). A/B test of
    //     the occupancy-vs-intrinsic-2-phase-ceiling hypothesis. ---
    mfma_g<128, 64, 32, 1, true, 4, true><<<dim3(16, 4, 16), blk, 0, stream>>>(
        Acat, 1048576, 0, 2048, Pcat, 2097152, 0, 2048, bfu, 0,
        fused, 524288, 0, 1024, 2048, 1.0f, part);

    // --- BN finalize + apply + ReLU (single kernel, 512 stat slots) ---
    bn_apply_f<<<4096, blk, 0, stream>>>(fused, part, gamma, beta, out);
}

// Round 17
// 166.470 us; speedup vs baseline: 1.1029x; 1.1029x over previous
//
#include <hip/hip_runtime.h>
#include <math.h>

#define NB 16
#define CC 512
#define CQ 64
#define HWN 1024

typedef float4 f4;
typedef __bf16 bf16x8 __attribute__((ext_vector_type(8)));
typedef float f32x4 __attribute__((ext_vector_type(4)));
typedef __attribute__((ext_vector_type(8))) unsigned short ushort8v;

__device__ __forceinline__ unsigned short f2bf(float f) {
    unsigned int u = __float_as_uint(f);
    u = (u + 0x7fffu + ((u >> 16) & 1u)) >> 16;
    return (unsigned short)u;
}
__device__ __forceinline__ float bf2f(unsigned short u) {
    return __uint_as_float(((unsigned int)u) << 16);
}

__device__ __forceinline__ void gload16(const unsigned short* g, unsigned short* l) {
    __builtin_amdgcn_global_load_lds(
        (const __attribute__((address_space(1))) unsigned int*)g,
        (__attribute__((address_space(3))) unsigned int*)l,
        16, 0, 0);
}

// ---------------------------------------------------------------------------
// Generalized NT bf16 MFMA GEMM, 2-phase double-buffered (validated r5-r16).
// BK in {64,32}. Swizzle involutions (r13-verified, 0 conflicts):
//   BK=64: f(r) = r & 7
//   BK=32: f(r) = (r>>1) & 3
// r16 A/B concluded: fuse is bound by per-step LDS/issue cost vs MFMA work
// (2-phase structural ceiling ~680 TF), NOT occupancy — BN=128/BK=64 is the
// optimal fuse config. STATS partials to unique slots (no atomics).
// ---------------------------------------------------------------------------
template<int BM, int BN, int BK, int BIAS, bool OBF16, int ZSH, bool STATS>
__global__ __launch_bounds__(256)
void mfma_g(const unsigned short* __restrict__ A, long sAlo, long sAhi, int lda,
            const unsigned short* __restrict__ B, long sBlo, long sBhi, int ldb,
            const float* __restrict__ bias, long sBiasHi,
            void* __restrict__ Cout, long sClo, long sChi, int ldc,
            int Ksize, float alpha, float* __restrict__ statsAcc)
{
    constexpr int MF  = BM / 32;           // 16-row frags per wave (M)
    constexpr int NF  = BN / 32;
    constexpr int LPR = BK / 8;            // lanes per LDS row (8 or 4)
    constexpr int RPG = 64 / LPR;          // rows per gload (8 or 16)
    constexpr int CA  = BM / RPG / 4;      // gloads per wave for A
    constexpr int CB  = BN / RPG / 4;
    constexpr int SWM = LPR - 1;           // swizzle mask (7 or 3)
    constexpr int SSH = (BK == 64) ? 0 : 1; // swizzle row shift
    __shared__ unsigned short As[2][BM * BK];
    __shared__ unsigned short Bs[2][BN * BK];

    // XCD-chunked bijective swizzle: physical p -> logical (p%8)*(n/8)+p/8
    const int gx = gridDim.x, gy = gridDim.y;
    int f = blockIdx.x + gx * (blockIdx.y + gy * blockIdx.z);
    const int nwg = gx * gy * gridDim.z;
    f = (f & 7) * (nwg >> 3) + (f >> 3);
    const int bx = f % gx; const int t2 = f / gx;
    const int by = t2 % gy; const int bz = t2 / gy;

    const int zlo = ZSH ? (bz & ((1 << ZSH) - 1)) : 0;
    const int zhi = bz >> ZSH;

    const int t = threadIdx.x, lane = t & 63, wid = t >> 6;
    const int wm = (wid >> 1) * (BM / 2), wn = (wid & 1) * (BN / 2);
    const int m0 = by * BM, n0 = bx * BN;
    const unsigned short* Ab = A + (long)zlo * sAlo + (long)zhi * sAhi;
    const unsigned short* Bb = B + (long)zlo * sBlo + (long)zhi * sBhi;

    // staging: each gload = RPG rows x BK*2 bytes; source col pre-swizzled
    const int srow = lane / LPR;                 // row within gload
    const int slt  = lane & SWM;                 // 16B slot
    const int scol = ((slt ^ ((srow >> SSH) & SWM)) << 3);
    const unsigned short* gA[CA]; const unsigned short* gB[CB];
    unsigned short* lA[CA]; unsigned short* lB[CB];
#pragma unroll
    for (int c = 0; c < CA; ++c) {
        const int seg = wid + 4 * c;
        gA[c] = Ab + (long)(m0 + seg * RPG + srow) * lda + scol;
        lA[c] = &As[0][seg * 512];               // RPG*BK = 512 ushorts always
    }
#pragma unroll
    for (int c = 0; c < CB; ++c) {
        const int seg = wid + 4 * c;
        gB[c] = Bb + (long)(n0 + seg * RPG + srow) * ldb + scol;
        lB[c] = &Bs[0][seg * 512];
    }

    f32x4 acc[MF][NF] = {};
    const int l15 = lane & 15, q = lane >> 4;    // k-octet 0..3

    // prologue: stage tile 0 into buf 0, drain
#pragma unroll
    for (int c = 0; c < CA; ++c) gload16(gA[c], lA[c]);
#pragma unroll
    for (int c = 0; c < CB; ++c) gload16(gB[c], lB[c]);
    __syncthreads();

    const int nt = Ksize / BK;
    int cur = 0;
    for (int tt = 0; tt < nt; ++tt) {
        if (tt + 1 < nt) {                       // issue next-tile loads FIRST
            const int ko = (tt + 1) * BK;
            const int nb = cur ^ 1;
#pragma unroll
            for (int c = 0; c < CA; ++c) gload16(gA[c] + ko, lA[c] + nb * (BM * BK));
#pragma unroll
            for (int c = 0; c < CB; ++c) gload16(gB[c] + ko, lB[c] + nb * (BN * BK));
        }
        if (BK == 64) {
            bf16x8 alo[MF], ahi[MF], blo[NF], bhi[NF];
#pragma unroll
            for (int i = 0; i < MF; ++i) {
                const int r = wm + i * 16 + l15;
                alo[i] = *(const bf16x8*)&As[cur][r * 64 + ((q ^ (r & 7)) << 3)];
                ahi[i] = *(const bf16x8*)&As[cur][r * 64 + (((q + 4) ^ (r & 7)) << 3)];
            }
#pragma unroll
            for (int j = 0; j < NF; ++j) {
                const int r = wn + j * 16 + l15;
                blo[j] = *(const bf16x8*)&Bs[cur][r * 64 + ((q ^ (r & 7)) << 3)];
                bhi[j] = *(const bf16x8*)&Bs[cur][r * 64 + (((q + 4) ^ (r & 7)) << 3)];
            }
#pragma unroll
            for (int i = 0; i < MF; ++i)
#pragma unroll
                for (int j = 0; j < NF; ++j) {
                    acc[i][j] = __builtin_amdgcn_mfma_f32_16x16x32_bf16(alo[i], blo[j], acc[i][j], 0, 0, 0);
                    acc[i][j] = __builtin_amdgcn_mfma_f32_16x16x32_bf16(ahi[i], bhi[j], acc[i][j], 0, 0, 0);
                }
        } else {                                 // BK == 32, f(r) = (r>>1)&3
            bf16x8 av[MF], bv[NF];
#pragma unroll
            for (int i = 0; i < MF; ++i) {
                const int r = wm + i * 16 + l15;
                av[i] = *(const bf16x8*)&As[cur][r * 32 + ((q ^ ((r >> 1) & 3)) << 3)];
            }
#pragma unroll
            for (int j = 0; j < NF; ++j) {
                const int r = wn + j * 16 + l15;
                bv[j] = *(const bf16x8*)&Bs[cur][r * 32 + ((q ^ ((r >> 1) & 3)) << 3)];
            }
#pragma unroll
            for (int i = 0; i < MF; ++i)
#pragma unroll
                for (int j = 0; j < NF; ++j)
                    acc[i][j] = __builtin_amdgcn_mfma_f32_16x16x32_bf16(av[i], bv[j], acc[i][j], 0, 0, 0);
        }
        __syncthreads();                         // drains vmcnt: next buf ready
        cur ^= 1;
    }

    unsigned short* C16 = (unsigned short*)Cout + (long)zlo * sClo + (long)zhi * sChi;
    float*          C32 = (float*)Cout + (long)zlo * sClo + (long)zhi * sChi;
    const float* biasb = (BIAS != 0) ? bias + (long)zhi * sBiasHi : nullptr;
    const int r0 = q << 2;
#pragma unroll
    for (int i = 0; i < MF; ++i) {
#pragma unroll
        for (int r = 0; r < 4; ++r) {
            const int m = m0 + wm + i * 16 + r0 + r;
            const float brow = (BIAS == 1) ? biasb[m] : 0.0f;
            float ps = 0.0f, ps2 = 0.0f;
#pragma unroll
            for (int j = 0; j < NF; ++j) {
                const int n = n0 + wn + j * 16 + l15;
                const float bb = (BIAS == 2) ? biasb[n] : brow;
                const float o = alpha * (acc[i][j][r] + bb);
                if (OBF16) C16[(long)m * ldc + n] = f2bf(o);
                else       C32[(long)m * ldc + n] = o;
                if (STATS) { ps += o; ps2 += o * o; }   // pre-rounding fp32 stats
            }
            if (STATS) {
#pragma unroll
                for (int off = 8; off; off >>= 1) {
                    ps  += __shfl_xor(ps, off);
                    ps2 += __shfl_xor(ps2, off);
                }
                if (l15 == 0) {
                    const int slot2 = ((zlo * gx + bx) << 1) + (wid & 1);  // < 256
                    statsAcc[(long)m * 256 + slot2]          = ps;
                    statsAcc[131072 + (long)m * 256 + slot2] = ps2;
                }
            }
        }
    }
}

// ---------------------------------------------------------------------------
// Fused QK^T + softmax -> Pcat bf16, fully in-register (validated r10-r16).
// ---------------------------------------------------------------------------
__global__ __launch_bounds__(256)
void attn_fused3(const unsigned short* __restrict__ QK, unsigned short* __restrict__ Pcat)
{
    __shared__ float ws16[16][4];   // [row][wave] partial sums
    const int t = threadIdx.x, lane = t & 63, w = t >> 6;
    const int bx = blockIdx.x, b = blockIdx.y, dir = blockIdx.z;
    const unsigned short* Q = QK + (long)(dir ? b : 16 + b) * 131072;
    const unsigned short* K = QK + (long)(dir ? 16 + b : b) * 131072 + 64;
    const int l15 = lane & 15, slot = lane >> 4, kg = slot << 3;

    const long mrow = (long)bx * 16 + l15;
    bf16x8 aq0 = *(const bf16x8*)&Q[mrow * 128 + kg];
    bf16x8 aq1 = *(const bf16x8*)&Q[mrow * 128 + 32 + kg];

    const int colbase = w << 8;       // wave covers 256 kv cols
    const int rbase = slot << 2;
    f32x4 e[4][4];                    // e[c][j][r], static indexing only
    float rowp[4] = {0.0f, 0.0f, 0.0f, 0.0f};
#pragma unroll
    for (int c = 0; c < 4; ++c) {
        const int n0 = colbase + (c << 6);
        bf16x8 bk0[4], bk1[4];
#pragma unroll
        for (int j = 0; j < 4; ++j) {
            const long krow = n0 + (j << 4) + l15;
            bk0[j] = *(const bf16x8*)&K[krow * 128 + kg];
            bk1[j] = *(const bf16x8*)&K[krow * 128 + 32 + kg];
        }
#pragma unroll
        for (int j = 0; j < 4; ++j) {
            f32x4 a = {0.f, 0.f, 0.f, 0.f};
            a = __builtin_amdgcn_mfma_f32_16x16x32_bf16(aq0, bk0[j], a, 0, 0, 0);
            a = __builtin_amdgcn_mfma_f32_16x16x32_bf16(aq1, bk1[j], a, 0, 0, 0);
#pragma unroll
            for (int r = 0; r < 4; ++r) {
                const float ev = __expf(a[r]);
                e[c][j][r] = ev;
                rowp[r] += ev;
            }
        }
    }
#pragma unroll
    for (int off = 1; off < 16; off <<= 1) {
#pragma unroll
        for (int r = 0; r < 4; ++r) rowp[r] += __shfl_xor(rowp[r], off);
    }
    if (l15 == 0) {
#pragma unroll
        for (int r = 0; r < 4; ++r) ws16[rbase + r][w] = rowp[r];
    }
    __syncthreads();
    float inv[4];
#pragma unroll
    for (int r = 0; r < 4; ++r) {
        f4 s = *(const f4*)ws16[rbase + r];
        inv[r] = 1.0f / (s.x + s.y + s.z + s.w);
    }
    unsigned short* dstb = Pcat + ((long)(b * 1024 + bx * 16)) * 2048 + dir * 1024;
#pragma unroll
    for (int c = 0; c < 4; ++c) {
#pragma unroll
        for (int j = 0; j < 4; ++j) {
            const int col = colbase + (c << 6) + (j << 4) + l15;
#pragma unroll
            for (int r = 0; r < 4; ++r)
                dstb[(long)(rbase + r) * 2048 + col] = f2bf(e[c][j][r] * inv[r]);
        }
    }
}

// ---------------------------------------------------------------------------
// ALL prep in ONE dispatch (5377 blocks) — validated r12-r16.
// ---------------------------------------------------------------------------
__global__ __launch_bounds__(256)
void prep_all(const float* __restrict__ src_dep, const float* __restrict__ src_rgb,
              const float* __restrict__ Wv_dep, const float* __restrict__ Wv_rgb,
              const float* __restrict__ W_fuse,
              const float* __restrict__ wqd, const float* __restrict__ wkd,
              const float* __restrict__ wqr, const float* __restrict__ wkr,
              const float* __restrict__ bqd, const float* __restrict__ bkd,
              const float* __restrict__ bqr, const float* __restrict__ bkr,
              const float* __restrict__ bvd, const float* __restrict__ bvr,
              unsigned short* __restrict__ xT, unsigned short* __restrict__ WvT,
              unsigned short* __restrict__ Wfb, unsigned short* __restrict__ Wqk,
              float* __restrict__ bfuse, float* __restrict__ biascat, float s)
{
    __shared__ float tile[64][65];
    const int blk = blockIdx.x, t = threadIdx.x;

    if (blk < 4096) {                      // input transpose pair
        const int z = blk >> 7, rem = blk & 127;
        const int c0 = (rem & 15) << 6, r0 = (rem >> 4) << 6;
        const float* sp = (z < 16 ? src_dep : src_rgb) + (long)(z & 15) * 524288;
        unsigned short* d = xT + (long)z * 524288;
        const int lr = t >> 4, lc = (t & 15) << 2;
#pragma unroll
        for (int i = 0; i < 4; ++i) {
            f4 v = *(const f4*)(sp + (long)(r0 + lr + i * 16) * HWN + c0 + lc);
            *(f4*)&tile[lr + i * 16][lc] = v;
        }
        __syncthreads();
#pragma unroll
        for (int i = 0; i < 4; ++i) {
            const int crow = lr + i * 16;
            ushort4 o;
            o.x = f2bf(tile[lc + 0][crow]);
            o.y = f2bf(tile[lc + 1][crow]);
            o.z = f2bf(tile[lc + 2][crow]);
            o.w = f2bf(tile[lc + 3][crow]);
            *(ushort4*)&d[(long)(c0 + crow) * CC + r0 + lc] = o;
        }
    } else if (blk < 4224) {               // Wv transpose pair
        const int bb = blk - 4096;
        const int z = bb >> 6, tx = bb & 63;
        const float* src = z ? Wv_rgb : Wv_dep;
        unsigned short* d = WvT + (long)z * 262144;
        const int c0 = (tx & 7) << 6, r0 = (tx >> 3) << 6;
        const int lr = t >> 4, lc = (t & 15) << 2;
#pragma unroll
        for (int i = 0; i < 4; ++i) {
            f4 v = *(const f4*)(src + (long)(r0 + lr + i * 16) * CC + c0 + lc);
            *(f4*)&tile[lr + i * 16][lc] = v;
        }
        __syncthreads();
#pragma unroll
        for (int i = 0; i < 4; ++i) {
            const int crow = lr + i * 16;
            ushort4 o;
            o.x = f2bf(tile[lc + 0][crow]);
            o.y = f2bf(tile[lc + 1][crow]);
            o.z = f2bf(tile[lc + 2][crow]);
            o.w = f2bf(tile[lc + 3][crow]);
            *(ushort4*)&d[(long)(c0 + crow) * CC + r0 + lc] = o;
        }
    } else if (blk < 4736) {               // W_fuse flat cvt
        const int i4 = (blk - 4224) * 256 + t;
        f4 v = ((const f4*)W_fuse)[i4];
        ushort4 o;
        o.x = f2bf(v.x); o.y = f2bf(v.y); o.z = f2bf(v.z); o.w = f2bf(v.w);
        ((ushort4*)Wfb)[i4] = o;
    } else if (blk < 4864) {               // Wqk build
        const int i4 = (blk - 4736) * 256 + t;
        const int row = i4 >> 7;
        const int seg = row >> 6;
        const float* src = (seg == 0) ? wqd : (seg == 1) ? wkd : (seg == 2) ? wqr : wkr;
        const float sc = (seg & 1) ? 1.0f : s;
        f4 v = ((const f4*)src)[((row & 63) << 7) + (i4 & 127)];
        ushort4 o;
        o.x = f2bf(v.x * sc); o.y = f2bf(v.y * sc);
        o.z = f2bf(v.z * sc); o.w = f2bf(v.w * sc);
        ((ushort4*)Wqk)[i4] = o;
    } else if (blk < 5376) {               // bfuse
        const int o = blk - 4864;
        const float* row = W_fuse + (long)o * 1024;
        float sum = row[t] * bvd[t] + row[512 + t] * bvr[t]
                  + row[256 + t] * bvd[256 + t] + row[768 + t] * bvr[256 + t];
#pragma unroll
        for (int off = 32; off; off >>= 1) sum += __shfl_xor(sum, off);
        float* red = &tile[0][0];
        if ((t & 63) == 0) red[t >> 6] = sum;
        __syncthreads();
        if (t == 0) bfuse[o] = red[0] + red[1] + red[2] + red[3];
    } else {                               // biascat
        float v;
        if (t < 64)       v = bqd[t] * s;
        else if (t < 128) v = bkd[t - 64];
        else if (t < 192) v = bqr[t - 128] * s;
        else              v = bkr[t - 192];
        biascat[t] = v;
    }
}

// ---------------------------------------------------------------------------
// BN finalize + apply + ReLU in ONE kernel (validated r11-r13), 256 slots.
// ---------------------------------------------------------------------------
__global__ __launch_bounds__(256)
void bn_apply_f(const unsigned short* __restrict__ fused, const float* __restrict__ part,
                const float* __restrict__ gamma, const float* __restrict__ beta,
                float* __restrict__ out)
{
    __shared__ float red[4][4];   // [stat: s1c0,s2c0,s1c1,s2c1][wave]
    const int t = threadIdx.x, blk = blockIdx.x;
    const int c0 = (blk * 2) & 511, c1 = c0 + 1;
    float a = part[(long)c0 * 256 + t];
    float b = part[131072 + (long)c0 * 256 + t];
    float c = part[(long)c1 * 256 + t];
    float d = part[131072 + (long)c1 * 256 + t];
#pragma unroll
    for (int off = 32; off; off >>= 1) {
        a += __shfl_xor(a, off); b += __shfl_xor(b, off);
        c += __shfl_xor(c, off); d += __shfl_xor(d, off);
    }
    if ((t & 63) == 0) {
        const int w = t >> 6;
        red[0][w] = a; red[1][w] = b; red[2][w] = c; red[3][w] = d;
    }
    __syncthreads();
    const float S1a = red[0][0] + red[0][1] + red[0][2] + red[0][3];
    const float S2a = red[1][0] + red[1][1] + red[1][2] + red[1][3];
    const float S1b = red[2][0] + red[2][1] + red[2][2] + red[2][3];
    const float S2b = red[3][0] + red[3][1] + red[3][2] + red[3][3];
    const float mean0 = S1a * (1.0f / 16384.0f);
    const float is0   = rsqrtf(S2a * (1.0f / 16384.0f) - mean0 * mean0 + 1e-5f);
    const float mean1 = S1b * (1.0f / 16384.0f);
    const float is1   = rsqrtf(S2b * (1.0f / 16384.0f) - mean1 * mean1 + 1e-5f);

    const long i8 = (long)blk * 256 + t;         // ushort8 index
    const int  oc = (t >> 7) ? c1 : c0;
    const float mean = (t >> 7) ? mean1 : mean0;
    const float is   = (t >> 7) ? is1 : is0;
    ushort8v v = ((const ushort8v*)fused)[i8];
    const float g  = gamma[oc] * is;
    const float bb = beta[oc] - mean * g;
    f4 o0, o1;
    o0.x = fmaxf(fmaf(bf2f(v[0]), g, bb), 0.0f);
    o0.y = fmaxf(fmaf(bf2f(v[1]), g, bb), 0.0f);
    o0.z = fmaxf(fmaf(bf2f(v[2]), g, bb), 0.0f);
    o0.w = fmaxf(fmaf(bf2f(v[3]), g, bb), 0.0f);
    o1.x = fmaxf(fmaf(bf2f(v[4]), g, bb), 0.0f);
    o1.y = fmaxf(fmaf(bf2f(v[5]), g, bb), 0.0f);
    o1.z = fmaxf(fmaf(bf2f(v[6]), g, bb), 0.0f);
    o1.w = fmaxf(fmaf(bf2f(v[7]), g, bb), 0.0f);
    ((f4*)out)[i8 * 2]     = o0;
    ((f4*)out)[i8 * 2 + 1] = o1;
}

// ---------------------------------------------------------------------------
// Workspace layout (BYTE offsets). Total ~181 MB (< 218 MB proven available).
// ---------------------------------------------------------------------------
static constexpr long B_depT  = 0;          // bf16 (16,1024,512)
static constexpr long B_rgbT  = 16777216;
static constexpr long B_WvT1  = 33554432;   // bf16 512x512 (+WvT2 adjacent)
static constexpr long B_Wfb   = 34603008;   // bf16 512x1024
static constexpr long B_Wqk   = 35651584;   // bf16 256x512
static constexpr long B_Wc1   = 35913728;   // bf16 512x512 (+Wc2 adjacent)
static constexpr long B_bfu   = 36962304;   // fp32 512
static constexpr long B_bias  = 36964352;   // fp32 256
static constexpr long B_QK    = 36966400;   // bf16 (32,1024,128)
static constexpr long B_Acat  = 45355008;   // bf16 (16,512,2048)
static constexpr long B_Pcat  = 78909440;   // bf16 (16,1024,2048)
static constexpr long B_fused = 146018304;  // bf16 (16,512,1024)
static constexpr long B_part  = 179576832;  // fp32 262144 (sum[512x256] | sumsq)

extern "C" void kernel_launch(void* const* d_in, const int* in_sizes, int n_in,
                              void* d_out, int out_size, void* d_ws, size_t ws_size,
                              hipStream_t stream)
{
    const float* rgb    = (const float*)d_in[0];
    const float* depth  = (const float*)d_in[1];
    const float* Wq_rgb = (const float*)d_in[2];
    const float* bq_rgb = (const float*)d_in[3];
    const float* Wk_dep = (const float*)d_in[4];
    const float* bk_dep = (const float*)d_in[5];
    const float* Wv_dep = (const float*)d_in[6];
    const float* bv_dep = (const float*)d_in[7];
    const float* Wq_dep = (const float*)d_in[8];
    const float* bq_dep = (const float*)d_in[9];
    const float* Wk_rgb = (const float*)d_in[10];
    const float* bk_rgb = (const float*)d_in[11];
    const float* Wv_rgb = (const float*)d_in[12];
    const float* bv_rgb = (const float*)d_in[13];
    const float* W_fuse = (const float*)d_in[14];
    const float* gamma  = (const float*)d_in[15];
    const float* beta   = (const float*)d_in[16];
    char* ws = (char*)d_ws;
    float* out = (float*)d_out;

    const float inv_scale = 0.044194173824159223f;  // 1/sqrt(512)
    dim3 blk(256);

    unsigned short* depT = (unsigned short*)(ws + B_depT);
    unsigned short* WvT1 = (unsigned short*)(ws + B_WvT1);
    unsigned short* Wfb  = (unsigned short*)(ws + B_Wfb);
    unsigned short* Wqk  = (unsigned short*)(ws + B_Wqk);
    unsigned short* Wc1  = (unsigned short*)(ws + B_Wc1);
    float*          bfu  = (float*)(ws + B_bfu);
    float*          bias = (float*)(ws + B_bias);
    unsigned short* QK   = (unsigned short*)(ws + B_QK);
    unsigned short* Acat = (unsigned short*)(ws + B_Acat);
    unsigned short* Pcat = (unsigned short*)(ws + B_Pcat);
    unsigned short* fused= (unsigned short*)(ws + B_fused);
    float*          part = (float*)(ws + B_part);

    // --- single prep dispatch: input transpose + all weight prep ---
    prep_all<<<5377, blk, 0, stream>>>(depth, rgb, Wv_dep, Wv_rgb, W_fuse,
        Wq_dep, Wk_dep, Wq_rgb, Wk_rgb, bq_dep, bk_dep, bq_rgb, bk_rgb,
        bv_dep, bv_rgb, depT, WvT1, Wfb, Wqk, bfu, bias, inv_scale);

    // --- Wc pair (z=0: Wf[:,:512]@Wv_dep; z=1: Wf[:,512:]@Wv_rgb), BK=32 ---
    mfma_g<128, 128, 32, 0, true, 0, false><<<dim3(4, 4, 2), blk, 0, stream>>>(
        Wfb, 0, 512, 1024, WvT1, 0, 262144, 512, nullptr, 0,
        Wc1, 0, 262144, 512, 512, 1.0f, nullptr);

    // --- projections: BM=64, BK=32 -> grid 512 ---
    mfma_g<64, 128, 32, 2, true, 4, false><<<dim3(1, 16, 32), blk, 0, stream>>>(
        depT, 524288, 8388608, 512, Wqk, 0, 65536, 512, bias, 128,
        QK, 131072, 2097152, 128, 512, 1.0f, nullptr);

    // --- Acat: BK=32, 32KB LDS, 4 blocks/CU on 1024 blocks ---
    mfma_g<128, 128, 32, 0, true, 4, false><<<dim3(8, 4, 32), blk, 0, stream>>>(
        Wc1, 0, 262144, 512, depT, 524288, 8388608, 512, nullptr, 0,
        Acat, 1048576, 1024, 2048, 512, 1.0f, nullptr);

    // --- fused attention: QK^T + exp + in-register softmax -> Pcat ---
    attn_fused3<<<dim3(64, NB, 2), blk, 0, stream>>>(QK, Pcat);

    // --- fused(bf16) = Acat @ Pcat^T + bfuse (K=2048), BN=128/BK=64:
    //     r16 A/B proved this is the optimal fuse config (occupancy is not
    //     the lever; 2-phase structural ceiling ~680 TF). ---
    mfma_g<128, 128, 64, 1, true, 4, true><<<dim3(8, 4, 16), blk, 0, stream>>>(
        Acat, 1048576, 0, 2048, Pcat, 2097152, 0, 2048, bfu, 0,
        fused, 524288, 0, 1024, 2048, 1.0f, part);

    // --- BN finalize + apply + ReLU (single kernel) ---
    bn_apply_f<<<4096, blk, 0, stream>>>(fused, part, gamma, beta, out);
}